// Round 1
// baseline (448.816 us; speedup 1.0000x reference)
//
#include <hip/hip_runtime.h>

#define H 512
#define NSEG 64
#define CHUNK 256

// ---------------------------------------------------------------------------
// k1: segment sum + counts. batch_id is sorted, so each block (256 contiguous
// rows) spans ~1-2 segments. Accumulate runs in registers, flush with atomics
// only at segment boundaries. 4 row-groups x 128 lanes, float4 per lane
// (one 2048B row per group per iteration, perfectly coalesced).
// ---------------------------------------------------------------------------
__global__ __launch_bounds__(512) void k_segsum(
    const float4* __restrict__ hv, const int* __restrict__ bid,
    float* __restrict__ seg_sum, int* __restrict__ counts)
{
    __shared__ int sb[CHUNK];
    const int base = blockIdx.x * CHUNK;
    const int tid  = threadIdx.x;
    if (tid < CHUNK) sb[tid] = bid[base + tid];
    __syncthreads();

    const int g = tid >> 7;    // row-group 0..3
    const int q = tid & 127;   // float4 column 0..127

    float4 acc = make_float4(0.f, 0.f, 0.f, 0.f);
    int cur = sb[g];
    int cnt = 0;

    for (int i = 0; i < CHUNK / 4; ++i) {
        const int rl = g + (i << 2);
        const int s  = sb[rl];
        if (s != cur) {
            float* dst = seg_sum + cur * H + q * 4;
            atomicAdd(dst + 0, acc.x);
            atomicAdd(dst + 1, acc.y);
            atomicAdd(dst + 2, acc.z);
            atomicAdd(dst + 3, acc.w);
            if (q == 0) atomicAdd(counts + cur, cnt);
            acc = make_float4(0.f, 0.f, 0.f, 0.f);
            cnt = 0;
            cur = s;
        }
        const float4 v = hv[(size_t)(base + rl) * (H / 4) + q];
        acc.x += v.x; acc.y += v.y; acc.z += v.z; acc.w += v.w;
        ++cnt;
    }
    float* dst = seg_sum + cur * H + q * 4;
    atomicAdd(dst + 0, acc.x);
    atomicAdd(dst + 1, acc.y);
    atomicAdd(dst + 2, acc.z);
    atomicAdd(dst + 3, acc.w);
    if (q == 0) atomicAdd(counts + cur, cnt);
}

// ---------------------------------------------------------------------------
// k2: per-segment gated MLP. One block per segment (64 blocks, 512 threads).
// c_V row staged in LDS; each wave computes one output at a time via
// lane-split dot product (coalesced 256B reads of W rows) + shfl butterfly.
// ---------------------------------------------------------------------------
__global__ __launch_bounds__(512) void k_mlp(
    const float* __restrict__ seg_sum, const int* __restrict__ counts,
    const float* __restrict__ W1, const float* __restrict__ b1,
    const float* __restrict__ W2, const float* __restrict__ b2,
    float* __restrict__ gate)
{
    __shared__ float c[H];
    __shared__ float hd[H];
    const int s   = blockIdx.x;
    const int tid = threadIdx.x;

    const float cntf = fmaxf((float)counts[s], 1.0f);
    c[tid] = seg_sum[s * H + tid] / cntf;
    __syncthreads();

    const int w = tid >> 6;   // wave 0..7
    const int l = tid & 63;   // lane 0..63

    // layer 1: hdn = relu(c @ W1^T + b1)
    for (int jb = 0; jb < H / 8; ++jb) {
        const int j = jb * 8 + w;
        const float* __restrict__ wr = W1 + (size_t)j * H;
        float acc = 0.f;
        #pragma unroll
        for (int m = 0; m < H / 64; ++m)
            acc += c[m * 64 + l] * wr[m * 64 + l];
        #pragma unroll
        for (int off = 32; off > 0; off >>= 1)
            acc += __shfl_xor(acc, off, 64);
        if (l == 0) hd[j] = fmaxf(acc + b1[j], 0.f);
    }
    __syncthreads();

    // layer 2: gate = sigmoid(hdn @ W2^T + b2)
    for (int jb = 0; jb < H / 8; ++jb) {
        const int j = jb * 8 + w;
        const float* __restrict__ wr = W2 + (size_t)j * H;
        float acc = 0.f;
        #pragma unroll
        for (int m = 0; m < H / 64; ++m)
            acc += hd[m * 64 + l] * wr[m * 64 + l];
        #pragma unroll
        for (int off = 32; off > 0; off >>= 1)
            acc += __shfl_xor(acc, off, 64);
        if (l == 0) gate[s * H + j] = 1.0f / (1.0f + expf(-(acc + b2[j])));
    }
}

// ---------------------------------------------------------------------------
// k3: out[i][:] = h_V[i][:] * gate[batch_id[i]][:]. Grid-stride float4.
// gate (128 KB) + batch_id are cache-resident; HBM traffic = h_V read + write.
// ---------------------------------------------------------------------------
__global__ __launch_bounds__(256) void k_gate(
    const float4* __restrict__ hv, const int* __restrict__ bid,
    const float4* __restrict__ gate, float4* __restrict__ out,
    long long total4)
{
    const long long stride = (long long)gridDim.x * blockDim.x;
    for (long long idx = (long long)blockIdx.x * blockDim.x + threadIdx.x;
         idx < total4; idx += stride) {
        const int row = (int)(idx >> 7);      // H/4 = 128 float4 per row
        const int q   = (int)(idx & 127);
        const int s   = bid[row];
        const float4 v  = hv[idx];
        const float4 gv = gate[(size_t)s * (H / 4) + q];
        out[idx] = make_float4(v.x * gv.x, v.y * gv.y, v.z * gv.z, v.w * gv.w);
    }
}

extern "C" void kernel_launch(void* const* d_in, const int* in_sizes, int n_in,
                              void* d_out, int out_size, void* d_ws, size_t ws_size,
                              hipStream_t stream)
{
    const float* h_V      = (const float*)d_in[0];
    const int*   batch_id = (const int*)d_in[1];
    const float* W1       = (const float*)d_in[2];
    const float* b1       = (const float*)d_in[3];
    const float* W2       = (const float*)d_in[4];
    const float* b2       = (const float*)d_in[5];
    float*       out      = (float*)d_out;

    const int N = in_sizes[0] / H;   // 262144

    // workspace layout
    char*  ws       = (char*)d_ws;
    float* seg_sum  = (float*)ws;                      // 64*512*4 = 131072 B
    int*   counts   = (int*)(ws + 131072);             // 64*4     = 256 B
    float* gate     = (float*)(ws + 131072 + 256);     // 64*512*4 = 131072 B

    // zero accumulators (seg_sum + counts) each call
    hipMemsetAsync(d_ws, 0, 131072 + 256, stream);

    k_segsum<<<N / CHUNK, 512, 0, stream>>>(
        (const float4*)h_V, batch_id, seg_sum, counts);

    k_mlp<<<NSEG, 512, 0, stream>>>(seg_sum, counts, W1, b1, W2, b2, gate);

    const long long total4 = (long long)N * (H / 4);
    k_gate<<<2048, 256, 0, stream>>>(
        (const float4*)h_V, batch_id, (const float4*)gate, (float4*)out, total4);
}

// Round 2
// 397.099 us; speedup vs baseline: 1.1302x; 1.1302x over previous
//
#include <hip/hip_runtime.h>

#define H 512
#define NSEG 64
#define CHUNK 256

typedef float f4 __attribute__((ext_vector_type(4)));

__device__ __forceinline__ f4 ntload4(const f4* p) {
    return __builtin_nontemporal_load(p);
}
__device__ __forceinline__ void ntstore4(f4* p, f4 v) {
    __builtin_nontemporal_store(v, p);
}

// ---------------------------------------------------------------------------
// k1: segment sum + counts. batch_id sorted -> register run-length accumulate,
// atomic flush only on segment change (<=63 changes grid-wide). 4 row-groups
// x 128 lanes, unroll 2 (two independent 16B loads in flight per thread).
// Non-temporal loads: h_V is streamed, don't pollute L2/L3.
// ---------------------------------------------------------------------------
__global__ __launch_bounds__(512) void k_segsum(
    const f4* __restrict__ hv, const int* __restrict__ bid,
    float* __restrict__ seg_sum, int* __restrict__ counts)
{
    __shared__ int sb[CHUNK];
    const int base = blockIdx.x * CHUNK;
    const int tid  = threadIdx.x;
    if (tid < CHUNK) sb[tid] = bid[base + tid];
    __syncthreads();

    const int g = tid >> 7;    // row-group 0..3
    const int q = tid & 127;   // float4 column 0..127

    f4 acc = (f4)(0.f);
    int cur = sb[g];
    int cnt = 0;

    for (int i = 0; i < 64; i += 2) {
        const int r0 = g + (i << 2);
        const int r1 = r0 + 4;
        const f4 v0 = ntload4(hv + (size_t)(base + r0) * (H / 4) + q);
        const f4 v1 = ntload4(hv + (size_t)(base + r1) * (H / 4) + q);
        const int s0 = sb[r0];
        const int s1 = sb[r1];
        if (s0 != cur) {
            float* dst = seg_sum + cur * H + q * 4;
            atomicAdd(dst + 0, acc[0]); atomicAdd(dst + 1, acc[1]);
            atomicAdd(dst + 2, acc[2]); atomicAdd(dst + 3, acc[3]);
            if (q == 0) atomicAdd(counts + cur, cnt);
            acc = (f4)(0.f); cnt = 0; cur = s0;
        }
        acc += v0; ++cnt;
        if (s1 != cur) {
            float* dst = seg_sum + cur * H + q * 4;
            atomicAdd(dst + 0, acc[0]); atomicAdd(dst + 1, acc[1]);
            atomicAdd(dst + 2, acc[2]); atomicAdd(dst + 3, acc[3]);
            if (q == 0) atomicAdd(counts + cur, cnt);
            acc = (f4)(0.f); cnt = 0; cur = s1;
        }
        acc += v1; ++cnt;
    }
    float* dst = seg_sum + cur * H + q * 4;
    atomicAdd(dst + 0, acc[0]); atomicAdd(dst + 1, acc[1]);
    atomicAdd(dst + 2, acc[2]); atomicAdd(dst + 3, acc[3]);
    if (q == 0) atomicAdd(counts + cur, cnt);
}

// ---------------------------------------------------------------------------
// k2: per-segment gated MLP. One block per segment (64 blocks, 512 threads).
// Wave-per-output dot products, lane-split K, shfl butterfly reduce.
// ---------------------------------------------------------------------------
__global__ __launch_bounds__(512) void k_mlp(
    const float* __restrict__ seg_sum, const int* __restrict__ counts,
    const float* __restrict__ W1, const float* __restrict__ b1,
    const float* __restrict__ W2, const float* __restrict__ b2,
    float* __restrict__ gate)
{
    __shared__ float c[H];
    __shared__ float hd[H];
    const int s   = blockIdx.x;
    const int tid = threadIdx.x;

    const float cntf = fmaxf((float)counts[s], 1.0f);
    c[tid] = seg_sum[s * H + tid] / cntf;
    __syncthreads();

    const int w = tid >> 6;   // wave 0..7
    const int l = tid & 63;   // lane 0..63

    for (int jb = 0; jb < H / 8; ++jb) {
        const int j = jb * 8 + w;
        const float* __restrict__ wr = W1 + (size_t)j * H;
        float acc = 0.f;
        #pragma unroll
        for (int m = 0; m < H / 64; ++m)
            acc += c[m * 64 + l] * wr[m * 64 + l];
        #pragma unroll
        for (int off = 32; off > 0; off >>= 1)
            acc += __shfl_xor(acc, off, 64);
        if (l == 0) hd[j] = fmaxf(acc + b1[j], 0.f);
    }
    __syncthreads();

    for (int jb = 0; jb < H / 8; ++jb) {
        const int j = jb * 8 + w;
        const float* __restrict__ wr = W2 + (size_t)j * H;
        float acc = 0.f;
        #pragma unroll
        for (int m = 0; m < H / 64; ++m)
            acc += hd[m * 64 + l] * wr[m * 64 + l];
        #pragma unroll
        for (int off = 32; off > 0; off >>= 1)
            acc += __shfl_xor(acc, off, 64);
        if (l == 0) gate[s * H + j] = 1.0f / (1.0f + expf(-(acc + b2[j])));
    }
}

// ---------------------------------------------------------------------------
// k3: out[i][:] = h_V[i][:] * gate[batch_id[i]][:].
// Same chunked layout as k1: sorted batch_id -> gate f4 cached in a REGISTER,
// reloaded only on segment change. Pure stream: nt load h_V, nt store out,
// zero dependent loads in steady state. Unroll 2.
// ---------------------------------------------------------------------------
__global__ __launch_bounds__(512) void k_gate(
    const f4* __restrict__ hv, const int* __restrict__ bid,
    const f4* __restrict__ gate, f4* __restrict__ out)
{
    __shared__ int sb[CHUNK];
    const int base = blockIdx.x * CHUNK;
    const int tid  = threadIdx.x;
    if (tid < CHUNK) sb[tid] = bid[base + tid];
    __syncthreads();

    const int g = tid >> 7;
    const int q = tid & 127;

    int cur = sb[g];
    f4 gv = gate[(size_t)cur * (H / 4) + q];

    for (int i = 0; i < 64; i += 2) {
        const int r0 = g + (i << 2);
        const int r1 = r0 + 4;
        const f4 v0 = ntload4(hv + (size_t)(base + r0) * (H / 4) + q);
        const f4 v1 = ntload4(hv + (size_t)(base + r1) * (H / 4) + q);
        const int s0 = sb[r0];
        const int s1 = sb[r1];
        if (s0 != cur) { cur = s0; gv = gate[(size_t)cur * (H / 4) + q]; }
        ntstore4(out + (size_t)(base + r0) * (H / 4) + q, v0 * gv);
        if (s1 != cur) { cur = s1; gv = gate[(size_t)cur * (H / 4) + q]; }
        ntstore4(out + (size_t)(base + r1) * (H / 4) + q, v1 * gv);
    }
}

extern "C" void kernel_launch(void* const* d_in, const int* in_sizes, int n_in,
                              void* d_out, int out_size, void* d_ws, size_t ws_size,
                              hipStream_t stream)
{
    const float* h_V      = (const float*)d_in[0];
    const int*   batch_id = (const int*)d_in[1];
    const float* W1       = (const float*)d_in[2];
    const float* b1       = (const float*)d_in[3];
    const float* W2       = (const float*)d_in[4];
    const float* b2       = (const float*)d_in[5];

    const int N = in_sizes[0] / H;   // 262144

    char*  ws       = (char*)d_ws;
    float* seg_sum  = (float*)ws;                      // 64*512*4 = 131072 B
    int*   counts   = (int*)(ws + 131072);             // 64*4     = 256 B
    float* gate     = (float*)(ws + 131072 + 256);     // 64*512*4 = 131072 B

    hipMemsetAsync(d_ws, 0, 131072 + 256, stream);

    k_segsum<<<N / CHUNK, 512, 0, stream>>>(
        (const f4*)h_V, batch_id, seg_sum, counts);

    k_mlp<<<NSEG, 512, 0, stream>>>(seg_sum, counts, W1, b1, W2, b2, gate);

    k_gate<<<N / CHUNK, 512, 0, stream>>>(
        (const f4*)h_V, batch_id, (const f4*)gate, (f4*)d_out);
}